// Round 1
// baseline (338.342 us; speedup 1.0000x reference)
//
#include <hip/hip_runtime.h>
#include <hip/hip_bf16.h>

using bf16 = __hip_bfloat16;
typedef __attribute__((ext_vector_type(8))) short bf16x8;   // 8 bf16 = 4 VGPRs (MFMA A/B frag)
typedef __attribute__((ext_vector_type(4))) float f32x4;    // MFMA C/D frag

#define DEV __device__ __forceinline__

DEV void gload_lds16(const void* g, void* l) {
  __builtin_amdgcn_global_load_lds((const __attribute__((address_space(1))) void*)g,
                                   (__attribute__((address_space(3))) void*)l, 16, 0, 0);
}

// ---------------------------------------------------------------- converts
__global__ __launch_bounds__(256) void cvt_kernel(const float* __restrict__ x,
                                                  bf16* __restrict__ y, int n8) {
  int i = blockIdx.x * 256 + threadIdx.x;
  if (i >= n8) return;
  const float4* xv = (const float4*)x;
  float4 a = xv[i * 2];
  float4 b = xv[i * 2 + 1];
  union { bf16 h[8]; uint4 v; } u;
  u.h[0] = __float2bfloat16(a.x); u.h[1] = __float2bfloat16(a.y);
  u.h[2] = __float2bfloat16(a.z); u.h[3] = __float2bfloat16(a.w);
  u.h[4] = __float2bfloat16(b.x); u.h[5] = __float2bfloat16(b.y);
  u.h[6] = __float2bfloat16(b.z); u.h[7] = __float2bfloat16(b.w);
  *(uint4*)&y[(size_t)i * 8] = u.v;
}

// W [K=1024][N=1024] f32  ->  WT [N][K] bf16
__global__ __launch_bounds__(256) void wtrans_kernel(const float* __restrict__ W,
                                                     bf16* __restrict__ WT) {
  __shared__ float tile[32][33];
  const int tx = threadIdx.x & 31, ty = threadIdx.x >> 5;  // 32 x 8
  const int n0 = blockIdx.x * 32, k0 = blockIdx.y * 32;
#pragma unroll
  for (int i = ty; i < 32; i += 8)
    tile[i][tx] = W[(size_t)(k0 + i) * 1024 + n0 + tx];
  __syncthreads();
#pragma unroll
  for (int i = ty; i < 32; i += 8)
    WT[(size_t)(n0 + i) * 1024 + k0 + tx] = __float2bfloat16(tile[tx][i]);
}

// v (projected, bf16 [4096][1024]) -> VT [bh=32][dh=64][S=2048]
__global__ __launch_bounds__(256) void vtrans_kernel(const bf16* __restrict__ v,
                                                     bf16* __restrict__ VT) {
  __shared__ bf16 tile[64 * 64];
  const int t = threadIdx.x;
  const int bh = blockIdx.y, b = bh >> 4, h = bh & 15;
  const int s0 = blockIdx.x * 64;
  const int r0 = t >> 3, c8 = t & 7;
#pragma unroll
  for (int it = 0; it < 2; ++it) {
    int r = it * 32 + r0;  // s row within tile
    uint4 d = *(const uint4*)&v[(size_t)(b * 2048 + s0 + r) * 1024 + h * 64 + c8 * 8];
    *(uint4*)&tile[r * 64 + ((c8 ^ (r >> 3)) * 8)] = d;   // swizzle on (row>>3)
  }
  __syncthreads();
#pragma unroll
  for (int it = 0; it < 2; ++it) {
    int d = it * 32 + r0;  // dh row
    int sc = c8 * 8;
    union { bf16 h[8]; uint4 v4; } u;
#pragma unroll
    for (int j = 0; j < 8; ++j) {
      int row = sc + j;
      u.h[j] = tile[row * 64 + (((d >> 3) ^ (row >> 3)) * 8) + (d & 7)];
    }
    *(uint4*)&VT[((size_t)bh * 64 + d) * 2048 + s0 + sc] = u.v4;
  }
}

// ---------------------------------------------------------------- GEMM 128x128, BK=32
// A [M][1024] bf16 row-major, BT [N=1024][1024] bf16 (B transposed), bias f32[N]
// out = relu(A@B + bias), OutT in {bf16, float}
template <typename OutT>
DEV void gemm128_core(const bf16* __restrict__ A, const bf16* __restrict__ BT,
                      const float* __restrict__ bias, OutT* __restrict__ out) {
  constexpr int K = 1024, N = 1024;
  __shared__ bf16 ldsA[128 * 32];
  __shared__ bf16 ldsB[128 * 32];
  const int t = threadIdx.x;
  const int lane = t & 63, wid = t >> 6;
  const int wr = wid >> 1, wc = wid & 1;
  const int fr = lane & 15, fko = (lane >> 4) * 8;
  const size_t mBase = (size_t)blockIdx.y * 128;
  const size_t nBase = (size_t)blockIdx.x * 128;

  const int srow = t >> 2;          // 0..63
  const int scol = (t & 3) * 8;     // 0/8/16/24
  const bf16* gA = A + (mBase + srow) * K + scol;
  const bf16* gB = BT + (nBase + srow) * K + scol;
  bf16* lA = ldsA + wid * 512;      // wave-uniform LDS dest (HW adds lane*16B)
  bf16* lB = ldsB + wid * 512;

  f32x4 acc[4][4];
#pragma unroll
  for (int i = 0; i < 4; ++i)
#pragma unroll
    for (int j = 0; j < 4; ++j) acc[i][j] = (f32x4){0.f, 0.f, 0.f, 0.f};

  for (int k0 = 0; k0 < K; k0 += 32) {
    gload_lds16(gA + k0, lA);
    gload_lds16(gA + 64 * K + k0, lA + 2048);
    gload_lds16(gB + k0, lB);
    gload_lds16(gB + 64 * K + k0, lB + 2048);
    asm volatile("s_waitcnt vmcnt(0)" ::: "memory");
    __syncthreads();

    bf16x8 aF[4], bF[4];
#pragma unroll
    for (int i = 0; i < 4; ++i)
      aF[i] = *(const bf16x8*)&ldsA[(wr * 64 + i * 16 + fr) * 32 + fko];
#pragma unroll
    for (int j = 0; j < 4; ++j)
      bF[j] = *(const bf16x8*)&ldsB[(wc * 64 + j * 16 + fr) * 32 + fko];
#pragma unroll
    for (int i = 0; i < 4; ++i)
#pragma unroll
      for (int j = 0; j < 4; ++j)
        acc[i][j] = __builtin_amdgcn_mfma_f32_16x16x32_bf16(aF[i], bF[j], acc[i][j], 0, 0, 0);
    __syncthreads();
  }

  const int orow = (int)mBase + wr * 64 + (lane >> 4) * 4;
  const int ocol = (int)nBase + wc * 64 + fr;
#pragma unroll
  for (int j = 0; j < 4; ++j) {
    const float bj = bias[ocol + j * 16];
#pragma unroll
    for (int i = 0; i < 4; ++i)
#pragma unroll
      for (int r = 0; r < 4; ++r) {
        float v = fmaxf(acc[i][j][r] + bj, 0.f);
        size_t idx = (size_t)(orow + i * 16 + r) * N + (ocol + j * 16);
        if constexpr (sizeof(OutT) == 2) out[idx] = __float2bfloat16(v);
        else out[idx] = v;
      }
  }
}

struct QKVArgs {
  const bf16* A[3];
  const bf16* BT[3];
  const float* bias[3];
  bf16* out[3];
};

__global__ __launch_bounds__(256) void gemm_qkv_kernel(QKVArgs args) {
  const int z = blockIdx.z;
  gemm128_core<bf16>(args.A[z], args.BT[z], args.bias[z], args.out[z]);
}

__global__ __launch_bounds__(256) void gemm_out_kernel(const bf16* __restrict__ A,
                                                       const bf16* __restrict__ BT,
                                                       const float* __restrict__ bias,
                                                       float* __restrict__ out) {
  gemm128_core<float>(A, BT, bias, out);
}

// ---------------------------------------------------------------- flash attention (causal)
// Q,K: bf16 [B*S][1024] (head h at cols h*64..), VT: bf16 [bh][64][2048]
// O: bf16 [B*S][1024]. Block: 128 q-rows (4 waves x 32), KV tiles of 64.
__global__ __launch_bounds__(256) void attn_kernel(const bf16* __restrict__ Qb,
                                                   const bf16* __restrict__ Kb,
                                                   const bf16* __restrict__ VTb,
                                                   bf16* __restrict__ Ob) {
  constexpr int Dm = 1024, S = 2048;
  __shared__ bf16 ldsK[64 * 64];
  __shared__ bf16 ldsV[64 * 64];
  __shared__ bf16 ldsP[4 * 32 * 64];
  const int t = threadIdx.x, lane = t & 63, wid = t >> 6;
  const int bh = blockIdx.y, b = bh >> 4, h = bh & 15;
  const int qb = blockIdx.x * 128;
  const int fr = lane & 15, fg = lane >> 4;
  const int qw = qb + wid * 32;
  const bf16* Qg = Qb + (size_t)b * S * Dm + h * 64;
  const bf16* Kg = Kb + (size_t)b * S * Dm + h * 64;
  const bf16* VTg = VTb + (size_t)bh * 64 * S;

  // Q fragments in registers (reused for all KV tiles)
  bf16x8 qF[2][2];
#pragma unroll
  for (int i = 0; i < 2; ++i)
#pragma unroll
    for (int kk = 0; kk < 2; ++kk)
      qF[i][kk] = *(const bf16x8*)&Qg[(size_t)(qw + i * 16 + fr) * Dm + kk * 32 + fg * 8];

  f32x4 oacc[2][4];
  float mrow[2][4], lrow[2][4];
#pragma unroll
  for (int i = 0; i < 2; ++i) {
#pragma unroll
    for (int n = 0; n < 4; ++n) oacc[i][n] = (f32x4){0.f, 0.f, 0.f, 0.f};
#pragma unroll
    for (int r = 0; r < 4; ++r) { mrow[i][r] = -3.0e38f; lrow[i][r] = 0.f; }
  }

  const int sr0 = t >> 3, sc8 = t & 7;
  const int nTiles = qb / 64 + 2;
  bf16* pbase = ldsP + wid * 2048;

  for (int tile = 0; tile < nTiles; ++tile) {
    const int kvb = tile * 64;
    // reg-stage K tile [64 kv][64 d] and VT tile [64 d][64 kv]
    uint4 kreg[2], vreg[2];
#pragma unroll
    for (int it = 0; it < 2; ++it) {
      int r = it * 32 + sr0;
      kreg[it] = *(const uint4*)&Kg[(size_t)(kvb + r) * Dm + sc8 * 8];
      vreg[it] = *(const uint4*)&VTg[(size_t)r * S + kvb + sc8 * 8];
    }
    __syncthreads();  // previous tile's LDS reads complete before overwrite
#pragma unroll
    for (int it = 0; it < 2; ++it) {
      int r = it * 32 + sr0;
      *(uint4*)&ldsK[r * 64 + ((sc8 ^ (r & 7)) * 8)] = kreg[it];  // XOR chunk swizzle
      *(uint4*)&ldsV[r * 64 + ((sc8 ^ (r & 7)) * 8)] = vreg[it];
    }
    __syncthreads();

    if (kvb <= qw + 31) {  // wave-uniform: this wave has unmasked work in tile
      // S = (Q K^T) — D[q][kv]
      f32x4 sf[2][4];
#pragma unroll
      for (int i = 0; i < 2; ++i)
#pragma unroll
        for (int n = 0; n < 4; ++n) sf[i][n] = (f32x4){0.f, 0.f, 0.f, 0.f};
#pragma unroll
      for (int n = 0; n < 4; ++n) {
#pragma unroll
        for (int kk = 0; kk < 2; ++kk) {
          bf16x8 kf = *(const bf16x8*)&ldsK[(n * 16 + fr) * 64 + (((kk * 4 + fg) ^ (fr & 7)) * 8)];
          sf[0][n] = __builtin_amdgcn_mfma_f32_16x16x32_bf16(qF[0][kk], kf, sf[0][n], 0, 0, 0);
          sf[1][n] = __builtin_amdgcn_mfma_f32_16x16x32_bf16(qF[1][kk], kf, sf[1][n], 0, 0, 0);
        }
      }
      const bool needmask = (kvb + 63 > qw);
#pragma unroll
      for (int i = 0; i < 2; ++i)
#pragma unroll
        for (int n = 0; n < 4; ++n)
#pragma unroll
          for (int r = 0; r < 4; ++r) {
            float vv = sf[i][n][r] * 0.125f;  // 1/sqrt(64)
            if (needmask) {
              int kv = kvb + n * 16 + fr;
              int qr = qw + i * 16 + fg * 4 + r;
              if (kv > qr) vv = -1e30f;
            }
            sf[i][n][r] = vv;
          }
      // online softmax per row (rows live in 16-lane groups)
#pragma unroll
      for (int i = 0; i < 2; ++i)
#pragma unroll
        for (int r = 0; r < 4; ++r) {
          float tmax = fmaxf(fmaxf(sf[i][0][r], sf[i][1][r]), fmaxf(sf[i][2][r], sf[i][3][r]));
          tmax = fmaxf(tmax, __shfl_xor(tmax, 1, 64));
          tmax = fmaxf(tmax, __shfl_xor(tmax, 2, 64));
          tmax = fmaxf(tmax, __shfl_xor(tmax, 4, 64));
          tmax = fmaxf(tmax, __shfl_xor(tmax, 8, 64));
          float mold = mrow[i][r];
          float mnew = fmaxf(mold, tmax);
          float corr = __expf(mold - mnew);
          mrow[i][r] = mnew;
          float rs = 0.f;
#pragma unroll
          for (int n = 0; n < 4; ++n) {
            float p = __expf(sf[i][n][r] - mnew);
            sf[i][n][r] = p;
            rs += p;
          }
          rs += __shfl_xor(rs, 1, 64);
          rs += __shfl_xor(rs, 2, 64);
          rs += __shfl_xor(rs, 4, 64);
          rs += __shfl_xor(rs, 8, 64);
          lrow[i][r] = lrow[i][r] * corr + rs;
#pragma unroll
          for (int n = 0; n < 4; ++n) oacc[i][n][r] *= corr;
        }
      // P -> LDS (bf16, swizzled) to re-shape D-layout into MFMA A-layout
#pragma unroll
      for (int i = 0; i < 2; ++i)
#pragma unroll
        for (int n = 0; n < 4; ++n)
#pragma unroll
          for (int r = 0; r < 4; ++r) {
            int prow = i * 16 + fg * 4 + r;
            int col = n * 16 + fr;
            pbase[prow * 64 + (((col >> 3) ^ (prow & 7)) * 8) + (col & 7)] =
                __float2bfloat16(sf[i][n][r]);
          }
      asm volatile("s_waitcnt lgkmcnt(0)" ::: "memory");
      // O += P V  — D[q][d]
#pragma unroll
      for (int ks = 0; ks < 2; ++ks) {
        bf16x8 pf[2], vf[4];
#pragma unroll
        for (int i = 0; i < 2; ++i)
          pf[i] = *(const bf16x8*)&pbase[(i * 16 + fr) * 64 + (((ks * 4 + fg) ^ (fr & 7)) * 8)];
#pragma unroll
        for (int n = 0; n < 4; ++n)
          vf[n] = *(const bf16x8*)&ldsV[(n * 16 + fr) * 64 + (((ks * 4 + fg) ^ (fr & 7)) * 8)];
#pragma unroll
        for (int i = 0; i < 2; ++i)
#pragma unroll
          for (int n = 0; n < 4; ++n)
            oacc[i][n] = __builtin_amdgcn_mfma_f32_16x16x32_bf16(pf[i], vf[n], oacc[i][n], 0, 0, 0);
      }
    }
  }
  // epilogue: normalize and store
#pragma unroll
  for (int i = 0; i < 2; ++i)
#pragma unroll
    for (int r = 0; r < 4; ++r) {
      float inv = 1.f / lrow[i][r];
      int row = qw + i * 16 + fg * 4 + r;
#pragma unroll
      for (int n = 0; n < 4; ++n) {
        float vv = oacc[i][n][r] * inv;
        Ob[((size_t)b * S + row) * Dm + h * 64 + n * 16 + fr] = __float2bfloat16(vv);
      }
    }
}

// ---------------------------------------------------------------- launch
extern "C" void kernel_launch(void* const* d_in, const int* in_sizes, int n_in,
                              void* d_out, int out_size, void* d_ws, size_t ws_size,
                              hipStream_t stream) {
  const float* query = (const float*)d_in[0];
  const float* key   = (const float*)d_in[1];
  const float* value = (const float*)d_in[2];
  const float* Wq = (const float*)d_in[3]; const float* bq = (const float*)d_in[4];
  const float* Wk = (const float*)d_in[5]; const float* bk = (const float*)d_in[6];
  const float* Wv = (const float*)d_in[7]; const float* bv = (const float*)d_in[8];
  const float* Wo = (const float*)d_in[9]; const float* bo = (const float*)d_in[10];
  float* out = (float*)d_out;

  char* ws = (char*)d_ws;
  const size_t MB = 1024 * 1024;
  bf16* xq  = (bf16*)(ws + 0 * MB);    // 8MB — later reused as VT
  bf16* xk  = (bf16*)(ws + 8 * MB);    // 8MB — later reused as attn buffer
  bf16* xv  = (bf16*)(ws + 16 * MB);   // 8MB
  bf16* qp  = (bf16*)(ws + 24 * MB);   // 8MB
  bf16* kp  = (bf16*)(ws + 32 * MB);   // 8MB
  bf16* vp  = (bf16*)(ws + 40 * MB);   // 8MB
  bf16* WqT = (bf16*)(ws + 48 * MB);   // 2MB each
  bf16* WkT = (bf16*)(ws + 50 * MB);
  bf16* WvT = (bf16*)(ws + 52 * MB);
  bf16* WoT = (bf16*)(ws + 54 * MB);
  bf16* VT   = xq;   // safe: xq consumed by gemm_qkv before vtrans runs
  bf16* attn = xk;   // safe: xk consumed by gemm_qkv before attn runs

  const int n8 = 2 * 2048 * 1024 / 8;  // 524288
  cvt_kernel<<<2048, 256, 0, stream>>>(query, xq, n8);
  cvt_kernel<<<2048, 256, 0, stream>>>(key, xk, n8);
  cvt_kernel<<<2048, 256, 0, stream>>>(value, xv, n8);

  dim3 wg(32, 32);
  wtrans_kernel<<<wg, 256, 0, stream>>>(Wq, WqT);
  wtrans_kernel<<<wg, 256, 0, stream>>>(Wk, WkT);
  wtrans_kernel<<<wg, 256, 0, stream>>>(Wv, WvT);
  wtrans_kernel<<<wg, 256, 0, stream>>>(Wo, WoT);

  QKVArgs qa;
  qa.A[0] = xq;  qa.A[1] = xk;  qa.A[2] = xv;
  qa.BT[0] = WqT; qa.BT[1] = WkT; qa.BT[2] = WvT;
  qa.bias[0] = bq; qa.bias[1] = bk; qa.bias[2] = bv;
  qa.out[0] = qp; qa.out[1] = kp; qa.out[2] = vp;
  gemm_qkv_kernel<<<dim3(8, 32, 3), 256, 0, stream>>>(qa);

  vtrans_kernel<<<dim3(32, 32), 256, 0, stream>>>(vp, VT);
  attn_kernel<<<dim3(16, 32), 256, 0, stream>>>(qp, kp, VT, attn);
  gemm_out_kernel<<<dim3(8, 32), 256, 0, stream>>>(attn, WoT, bo, out);
}